// Round 10
// baseline (97.625 us; speedup 1.0000x reference)
//
#include <hip/hip_runtime.h>
#include <stdint.h>

#define BS   16384
#define XRW  768
#define HD   256
#define DIN  1280
#define N4   1024
#define NKT  20   // 1280 / 64 K-tiles

typedef __attribute__((ext_vector_type(4))) float f32x4;
typedef __attribute__((ext_vector_type(8))) short s16x8;
typedef __attribute__((ext_vector_type(4))) unsigned int u32x4;

__device__ __forceinline__ unsigned short f2bf(float f) {
  uint32_t u = __builtin_bit_cast(uint32_t, f);
  u += 0x7FFFu + ((u >> 16) & 1u);   // RNE
  return (unsigned short)(u >> 16);
}
__device__ __forceinline__ uint32_t cvtpk(float a, float b) {
  uint32_t d;
  asm("v_cvt_pk_bf16_f32 %0, %1, %2" : "=v"(d) : "v"(a), "v"(b));
  return d;
}
__device__ __forceinline__ float sigmoidf_(float x) {
  return 1.0f / (1.0f + __expf(-x));
}
__device__ __forceinline__ float tanhf_(float x) {
  return 1.0f - 2.0f / (__expf(2.0f * x) + 1.0f);
}
__device__ __forceinline__ void gload16(const void* g, void* l) {
  __builtin_amdgcn_global_load_lds((const __attribute__((address_space(1))) void*)g,
                                   (__attribute__((address_space(3))) void*)l, 16, 0, 0);
}

// ---- Wt[n'][k] bf16 row-major; n' = (h>>4)*64 + g*16 + (h&15).
// Puts all 4 gates of one h into one wave's 4 fragments -> register epilogue.
__global__ void conv_w_kernel(const float* __restrict__ Wi,
                              const float* __restrict__ Wf,
                              const float* __restrict__ Wo,
                              const float* __restrict__ Ws,
                              unsigned short* __restrict__ Wt) {
  const int np = blockIdx.x;            // n' in [0,1024)
  const int g = (np >> 4) & 3;
  const int h = ((np >> 6) << 4) + (np & 15);
  const float* W = (g == 0) ? Wi : (g == 1) ? Wf : (g == 2) ? Wo : Ws;
  for (int k = threadIdx.x; k < DIN; k += 256)
    Wt[np * DIN + k] = f2bf(W[k * HD + h]);
}

// ---- 256x256 tile, BK=64, 8 waves (2M x 4N, 128x64 each).
// m201/m248-style 4-phase/K-tile: each phase = {ds_reads + stage issues ->
// s_barrier -> lgkmcnt(0) -> setprio(1) -> 16 MFMA (one C-quadrant x K=64) ->
// setprio(0) -> s_barrier}. B in 3 LDS buffers staged 2 tiles ahead; A
// reg-staged 1 tile ahead (f32 -> cvt_pk -> swizzled ds_write). NO explicit
// vmcnt in the main loop: AWRITE's register dependence on ALOAD makes the
// compiler emit the counted vmcnt(4) that retires B(t+1) before the tile-
// publish barrier (implicit T4). LDS = 2x32K A + 3x32K B = 160 KB.
__global__ __launch_bounds__(512, 2)
void lstm_gemm_kernel(const float* __restrict__ X,
                      const float* __restrict__ PT,
                      const float* __restrict__ PL,
                      const unsigned short* __restrict__ Wt,
                      const float* __restrict__ BI,
                      const float* __restrict__ BF,
                      const float* __restrict__ BO,
                      const float* __restrict__ BSv,
                      const float* __restrict__ OLD,
                      float* __restrict__ out) {
  __shared__ unsigned char smem[163840];  // A: 2x32KB @0; B: 3x32KB @64K
  const int tid  = threadIdx.x;
  const int wid  = tid >> 6;
  const int lane = tid & 63;

  // T1: XCD owns 8 contiguous M-panels x all 4 N-tiles; nt-siblings share A in L2.
  const int H = blockIdx.x;
  const int xcd = H & 7, slot = H >> 3;          // slot in [0,32)
  const int mt = xcd * 8 + (slot >> 2);          // [0,64)
  const int nt = slot & 3;                       // [0,4)
  const int wr = wid >> 2, wc = wid & 3;

  // ---- B staging (gload_lds, linear LDS dest, pre-swizzled source col)
  const int r8   = lane >> 3;
  const int scol = ((lane & 7) ^ r8) << 4;
  const char* gB = (const char*)Wt + (size_t)(nt * 256 + wid * 8 + r8) * (DIN * 2) + scol;

  // half h = rows h*128..h*128+127 = chunks {2h, 2h+1}
#define STAGE_BH(t1, bb, h) do {                                              \
    const int kb_ = (t1) * 128;                                               \
    _Pragma("unroll")                                                         \
    for (int c_ = 2 * (h); c_ < 2 * (h) + 2; ++c_)                            \
      gload16(gB + (size_t)c_ * (64 * DIN * 2) + kb_,                         \
              &smem[65536 + (bb) * 32768 + c_ * 8192 + wid * 1024]);          \
  } while (0)

  // ---- A reg staging: half h covers rows h*128 + {arow, arow+64}
  const int arow  = tid >> 3;
  const int a7    = tid & 7;
  const int awcol = ((a7 ^ (arow & 7)) << 4);

#define ALOAD(t1, h, R0, R1, R2, R3) do {                                     \
    const float* asrc_; int astr_, aoff_;                                     \
    if ((t1) < 12)      { asrc_ = X;  astr_ = XRW; aoff_ = (t1) * 64; }       \
    else if ((t1) < 16) { asrc_ = PT; astr_ = HD;  aoff_ = ((t1) - 12) * 64; }\
    else                { asrc_ = PL; astr_ = HD;  aoff_ = ((t1) - 16) * 64; }\
    const float* ga_ = asrc_ + (size_t)(mt * 256 + arow + (h) * 128) * astr_  \
                             + aoff_ + a7 * 8;                                \
    R0 = *(const f32x4*)(ga_);                                                \
    R1 = *(const f32x4*)(ga_ + 4);                                            \
    R2 = *(const f32x4*)(ga_ + (size_t)64 * astr_);                           \
    R3 = *(const f32x4*)(ga_ + (size_t)64 * astr_ + 4);                       \
  } while (0)

#define AWRITE(ab, h, R0, R1, R2, R3) do {                                    \
    u32x4 w0_, w1_;                                                           \
    w0_.x = cvtpk(R0.x, R0.y); w0_.y = cvtpk(R0.z, R0.w);                     \
    w0_.z = cvtpk(R1.x, R1.y); w0_.w = cvtpk(R1.z, R1.w);                     \
    w1_.x = cvtpk(R2.x, R2.y); w1_.y = cvtpk(R2.z, R2.w);                     \
    w1_.z = cvtpk(R3.x, R3.y); w1_.w = cvtpk(R3.z, R3.w);                     \
    *(u32x4*)(&smem[(ab) * 32768 + ((arow + (h) * 128)      << 7) + awcol]) = w0_; \
    *(u32x4*)(&smem[(ab) * 32768 + ((arow + (h) * 128 + 64) << 7) + awcol]) = w1_; \
  } while (0)

  // ---- frag read addressing (row&7 == lane&7 for all frags; conflict-free)
  const int rx   = lane & 15;
  const int axor = (lane & 7) << 4;
  const int col0 = (((lane >> 4) << 4)) ^ axor;        // kh=0
  const int col1 = (64 + ((lane >> 4) << 4)) ^ axor;   // kh=1
  const int aRow = (wr * 128 + rx) * 128;              // + ab*32768 + mh*8192 + mf*2048
  const int bRow = (wc * 64 + rx) * 128;               // + 65536 + bb*32768 + nh*4096 + nf*2048

  f32x4 acc[8][4];
  #pragma unroll
  for (int i = 0; i < 8; ++i)
    #pragma unroll
    for (int j = 0; j < 4; ++j) {
      f32x4 z = {0.0f, 0.0f, 0.0f, 0.0f};
      acc[i][j] = z;
    }

#define VMW(N) asm volatile("s_waitcnt vmcnt(" #N ")" ::: "memory")
#define LGKM0() do { asm volatile("s_waitcnt lgkmcnt(0)" ::: "memory");       \
                     __builtin_amdgcn_sched_barrier(0); } while (0)
#define RD_A(ab, mh) do {                                                     \
    _Pragma("unroll")                                                         \
    for (int mf = 0; mf < 4; ++mf) {                                          \
      aqh[mf * 2 + 0] = *(const s16x8*)(&smem[(ab) * 32768 + aRow + (mh) * 8192 + mf * 2048 + col0]); \
      aqh[mf * 2 + 1] = *(const s16x8*)(&smem[(ab) * 32768 + aRow + (mh) * 8192 + mf * 2048 + col1]); \
    }                                                                         \
  } while (0)
#define RD_B(bb, nh, BQ) do {                                                 \
    _Pragma("unroll")                                                         \
    for (int nf = 0; nf < 2; ++nf) {                                          \
      BQ[nf * 2 + 0] = *(const s16x8*)(&smem[65536 + (bb) * 32768 + bRow + (nh) * 4096 + nf * 2048 + col0]); \
      BQ[nf * 2 + 1] = *(const s16x8*)(&smem[65536 + (bb) * 32768 + bRow + (nh) * 4096 + nf * 2048 + col1]); \
    }                                                                         \
  } while (0)
#define QUAD(mh, nh, BQ) do {                                                 \
    __builtin_amdgcn_s_setprio(1);                                            \
    _Pragma("unroll")                                                         \
    for (int mf = 0; mf < 4; ++mf)                                            \
      _Pragma("unroll")                                                       \
      for (int nf = 0; nf < 2; ++nf)                                          \
        _Pragma("unroll")                                                     \
        for (int kh = 0; kh < 2; ++kh)                                        \
          acc[(mh) * 4 + mf][(nh) * 2 + nf] =                                 \
            __builtin_amdgcn_mfma_f32_16x16x32_bf16(aqh[mf * 2 + kh],         \
                BQ[nf * 2 + kh], acc[(mh) * 4 + mf][(nh) * 2 + nf], 0, 0, 0); \
    __builtin_amdgcn_s_setprio(0);                                            \
  } while (0)

  // 4 phases per K-tile. AB = A read buf (t&1), BB = B read buf (t%3),
  // BW = B stage buf ((t+2)%3). PFA: tile t+1 exists; PFB: tile t+2 exists.
#define TILE4(t1, AB, BB, BW, PFA, PFB) do {                                  \
    s16x8 aqh[8], bq0[4], bq1[4];                                             \
    f32x4 ar0, ar1, ar2, ar3, as0, as1, as2, as3;                             \
    /* P0: A(mh0) 8 + B(nh0) 4 reads; issue A(t+1)-H0 */                      \
    if (PFA) ALOAD((t1) + 1, 0, ar0, ar1, ar2, ar3);                          \
    RD_A(AB, 0);                                                              \
    RD_B(BB, 0, bq0);                                                         \
    __builtin_amdgcn_s_barrier();                                             \
    LGKM0();                                                                  \
    QUAD(0, 0, bq0);                                                          \
    __builtin_amdgcn_s_barrier();                                             \
    /* P1: B(nh1) 4 reads */                                                  \
    RD_B(BB, 1, bq1);                                                         \
    __builtin_amdgcn_s_barrier();                                             \
    LGKM0();                                                                  \
    QUAD(0, 1, bq1);                                                          \
    __builtin_amdgcn_s_barrier();                                             \
    /* P2: A(mh1) 8 reads; stage B(t+2)h0; A(t+1)-H1 issue; write A-H0 */     \
    if (PFB) STAGE_BH((t1) + 2, BW, 0);                                       \
    if (PFA) { AWRITE((AB) ^ 1, 0, ar0, ar1, ar2, ar3);                       \
               ALOAD((t1) + 1, 1, as0, as1, as2, as3); }                      \
    RD_A(AB, 1);                                                              \
    __builtin_amdgcn_s_barrier();                                             \
    LGKM0();                                                                  \
    QUAD(1, 1, bq1);                                                          \
    __builtin_amdgcn_s_barrier();                                             \
    /* P3: stage B(t+2)h1; write A-H1 (implicit vmcnt(4) retires B(t+1)); */  \
    /* publish; QUAD(1,0) overlaps next tile's read phase */                  \
    if (PFB) STAGE_BH((t1) + 2, BW, 1);                                       \
    if (PFA) AWRITE((AB) ^ 1, 1, as0, as1, as2, as3);                         \
    LGKM0();                                                                  \
    __builtin_amdgcn_s_barrier();                                             \
    QUAD(1, 0, bq0);                                                          \
  } while (0)

  // ---- prologue: A(0)->buf0; B(0)->b0, B(1)->b1
  {
    f32x4 p0, p1, p2, p3, q0, q1, q2, q3;
    ALOAD(0, 0, p0, p1, p2, p3);
    ALOAD(0, 1, q0, q1, q2, q3);
    STAGE_BH(0, 0, 0); STAGE_BH(0, 0, 1);
    STAGE_BH(1, 1, 0); STAGE_BH(1, 1, 1);
    AWRITE(0, 0, p0, p1, p2, p3);   // implicit waits on A regs
    AWRITE(0, 1, q0, q1, q2, q3);
    VMW(4);                          // B(0) landed (B(1) still in flight)
    LGKM0();
    __builtin_amdgcn_s_barrier();
  }

  // ---- main: tiles 0..17, unroll 6 for static (t&1, t%3, (t+2)%3)
  for (int j = 0; j < 18; j += 6) {
    TILE4(j + 0, 0, 0, 2, true, true);
    TILE4(j + 1, 1, 1, 0, true, true);
    TILE4(j + 2, 0, 2, 1, true, true);
    TILE4(j + 3, 1, 0, 2, true, true);
    TILE4(j + 4, 0, 1, 0, true, true);
    TILE4(j + 5, 1, 2, 1, true, true);
  }
  TILE4(18, 0, 0, 2, true, false);   // ALOAD(19)/AWRITE only; B(19) already staged
  TILE4(19, 1, 1, 0, false, false);  // pure compute

  // ---- pure-register epilogue: acc[mf][gate][r] holds all 4 gates of
  // (m = m0 + mf*16 + r, h = nt*64 + wc*16 + rx). 64B-coalesced per 16-lane group.
  {
    const int hq = nt * 64 + wc * 16 + rx;
    const float bbi = BI[hq], bbf = BF[hq], bbo = BO[hq], bbs = BSv[hq];
    const int m0 = mt * 256 + wr * 128 + (lane >> 4) * 4;
    float* outNS = out + (size_t)BS * HD;
    #pragma unroll
    for (int mf = 0; mf < 8; ++mf) {
      const int mrow = m0 + mf * 16;
      float old_[4];
      #pragma unroll
      for (int r = 0; r < 4; ++r)
        old_[r] = OLD[(size_t)(mrow + r) * HD + hq];
      #pragma unroll
      for (int r = 0; r < 4; ++r) {
        const float ig = sigmoidf_(acc[mf][0][r] + bbi);
        const float fg = sigmoidf_(acc[mf][1][r] + bbf);
        const float og = sigmoidf_(acc[mf][2][r] + bbo);
        const float cg = tanhf_(acc[mf][3][r] + bbs);
        const float ns = fg * old_[r] + ig * cg;
        const float nh = og * tanhf_(ns);
        out[(size_t)(mrow + r) * HD + hq]   = nh;
        outNS[(size_t)(mrow + r) * HD + hq] = ns;
      }
    }
  }
#undef STAGE_BH
#undef ALOAD
#undef AWRITE
#undef VMW
#undef LGKM0
#undef RD_A
#undef RD_B
#undef QUAD
#undef TILE4
}

extern "C" void kernel_launch(void* const* d_in, const int* in_sizes, int n_in,
                              void* d_out, int out_size, void* d_ws, size_t ws_size,
                              hipStream_t stream) {
  const float* X   = (const float*)d_in[0];
  const float* PT  = (const float*)d_in[1];
  const float* PL  = (const float*)d_in[2];
  const float* OLD = (const float*)d_in[3];
  const float* Wi  = (const float*)d_in[4];
  const float* bi  = (const float*)d_in[5];
  const float* Wf  = (const float*)d_in[6];
  const float* bfv = (const float*)d_in[7];
  const float* Wo  = (const float*)d_in[8];
  const float* bo  = (const float*)d_in[9];
  const float* Ws  = (const float*)d_in[10];
  const float* bsv = (const float*)d_in[11];
  float* out = (float*)d_out;

  unsigned short* Wt = (unsigned short*)d_ws;   // 1024*1280*2 = 2.62 MB

  conv_w_kernel<<<N4, 256, 0, stream>>>(Wi, Wf, Wo, Ws, Wt);
  lstm_gemm_kernel<<<256, 512, 0, stream>>>(X, PT, PL, Wt, bi, bfv, bo, bsv, OLD, out);
}